// Round 5
// baseline (574.316 us; speedup 1.0000x reference)
//
#include <hip/hip_runtime.h>
#include <hip/hip_bf16.h>

// Bahdanau attention, restructured:
//   tanh_in[b,t,k] = e[b,t,:]@(U@Wa) + cvec[b,k]   (one 131072x512x512 bf16 GEMM)
//   cij[b,t] = sum_k tanh(tanh_in)*V[k]            (fused epilogue, no [B,T,H] tensor)
//   alphas = softmax(cij); out = sum_t alphas*e
// Shapes: B=32 T=4096 D=512 H=512.
//
// R5: BARRIER-FREE GEMM K-loop. R2..R4's 2-barrier-per-BK structure plateaued
// at ~155us (all pipes 12-20%) -- the barrier coupling, not BW, was the wall
// (HBM floor is 43us). New structure: A staged ONCE (64x512 bf16 = 64KB LDS,
// single barrier), B stored in MFMA-fragment order and loaded straight from
// L2 into registers (coalesced 1KB/fragment, no LDS, no barriers). Main loop
// is pure per-wave dataflow with 1-deep B prefetch.
// Fixed harness overhead per replay (uncontrollable): ~160us 1GiB ws poison
// + ~80us input restore.

#define BB 32
#define TT 4096
#define DD 512
#define HH 512

typedef short s16x8 __attribute__((ext_vector_type(8)));
typedef float f32x4 __attribute__((ext_vector_type(4)));

union FU { float f; unsigned u; };

static __device__ __forceinline__ unsigned pack_bf16_trunc(float a, float b) {
    FU ua, ub; ua.f = a; ub.f = b;
    return (ua.u >> 16) | (ub.u & 0xffff0000u);
}

static __device__ __forceinline__ unsigned short f2bf_rne(float x) {
    FU v; v.f = x;
    unsigned u = v.u;
    u = u + 0x7fffu + ((u >> 16) & 1u);
    return (unsigned short)(u >> 16);
}

static __device__ __forceinline__ float tanh_fast(float x) {
    float e = __expf(2.0f * x);
    return 1.0f - 2.0f * __builtin_amdgcn_rcpf(e + 1.0f);
}

// ---------------------------------------------------------------------------
// k_prep, 96 blocks:
//  blocks 0..31  : cvec[b,:] = (hs[b]@W + bias)@Wa + ba   (per-batch, LDS, no atomics)
//  blocks 32..95 : UWa in MFMA-B-FRAGMENT order, 8 d-rows per block.
//    Fragment layout: frag (fn, fk) covers n in [fn*16,+16), k in [fk*32,+32);
//    lane L = (n&15) + 16*((k>>3)&3) holds bf16 for k&7 = 0..7 at
//    Btf[ ((fn*16+fk)*64 + L)*8 + (k&7) ].  One wave's fragment = contiguous 1KB.
__global__ void k_prep(const float* __restrict__ hs, const float* __restrict__ W,
                       const float* __restrict__ bias, const float* __restrict__ Wa,
                       const float* __restrict__ ba, const float* __restrict__ U,
                       float* __restrict__ cvec, unsigned short* __restrict__ Btf) {
    int bi = blockIdx.x;
    int tid = threadIdx.x;
    __shared__ float sm[8 * DD];
    if (bi < 32) {
        int b = bi;
        float* hsb = sm;
        float* gs = sm + DD;
        hsb[tid] = hs[b * DD + tid];
        hsb[tid + 256] = hs[b * DD + tid + 256];
        __syncthreads();
        float a0 = bias[tid], a1 = bias[tid + 256];
        #pragma unroll 4
        for (int d = 0; d < DD; ++d) {
            float h = hsb[d];
            a0 = fmaf(h, W[(size_t)d * HH + tid], a0);
            a1 = fmaf(h, W[(size_t)d * HH + tid + 256], a1);
        }
        gs[tid] = a0;
        gs[tid + 256] = a1;
        __syncthreads();
        float c0 = ba[tid], c1 = ba[tid + 256];
        #pragma unroll 4
        for (int h = 0; h < HH; ++h) {
            float g = gs[h];
            c0 = fmaf(g, Wa[(size_t)h * HH + tid], c0);
            c1 = fmaf(g, Wa[(size_t)h * HH + tid + 256], c1);
        }
        cvec[b * HH + tid] = c0;
        cvec[b * HH + tid + 256] = c1;
    } else {
        int d0 = (bi - 32) * 8;          // 8 consecutive k's, same fk & q group
        float (*Us)[DD] = (float (*)[DD])sm;
        #pragma unroll
        for (int i = 0; i < 16; ++i) {
            int idx = i * 256 + tid;
            Us[idx >> 9][idx & 511] = U[(size_t)(d0 + (idx >> 9)) * HH + (idx & 511)];
        }
        __syncthreads();
        float acc[8][2] = {};
        #pragma unroll 2
        for (int h = 0; h < DD; ++h) {
            float w0 = Wa[(size_t)h * HH + tid];
            float w1 = Wa[(size_t)h * HH + 256 + tid];
            #pragma unroll
            for (int dd = 0; dd < 8; ++dd) {
                float u = Us[dd][h];
                acc[dd][0] = fmaf(u, w0, acc[dd][0]);
                acc[dd][1] = fmaf(u, w1, acc[dd][1]);
            }
        }
        int fk = d0 >> 5, qq = (d0 >> 3) & 3;
        #pragma unroll
        for (int half = 0; half < 2; ++half) {
            int n = tid + half * 256;
            unsigned short tmp[8];
            #pragma unroll
            for (int dd = 0; dd < 8; ++dd) tmp[dd] = f2bf_rne(acc[dd][half]);
            size_t base = ((size_t)((n >> 4) * 16 + fk) * 64 + (n & 15) + (qq << 4)) * 8;
            *(uint4*)&Btf[base] = *(const uint4*)tmp;
        }
    }
}

// ---------------------------------------------------------------------------
// GEMM tile 64(M) x 512(N full), 2048 blocks x 256 thr (4 waves; wave w ->
// cols [w*128,+128)). A staged once: 64 rows x 512 k bf16 in LDS, XOR-swizzled
// 16B units (unit(m,c2) at m*64 + (c2^m); c2 = k/8). ONE barrier. Then each
// wave runs 16 k-steps of pure dataflow: 4 ds_read_b128 (af) + 8 register
// B-fragment loads from L2 (prefetched 1 step ahead) + 32 MFMA.
__global__ void __launch_bounds__(256, 2) k_gemm_tanh(
    const float* __restrict__ e, const unsigned short* __restrict__ Btf,
    const float* __restrict__ cvec, const float* __restrict__ V,
    float* __restrict__ cij) {
    int tid = threadIdx.x;
    int m0 = blockIdx.x * 64;
    int lane = tid & 63, w = tid >> 6;
    int wn = w * 128;
    int lcol = lane & 15, q = lane >> 4;

    __shared__ __align__(16) unsigned short As[64 * DD];   // 64 KB

    // ---- stage A once: 64 rows x 512 f32 -> bf16. per thread 16 units (32B src).
    const float* Abase = e + (size_t)m0 * DD;
    #pragma unroll
    for (int it = 0; it < 16; ++it) {
        int idx = it * 256 + tid;
        int m = idx >> 6, c2 = idx & 63;
        const float* p = Abase + (size_t)m * DD + c2 * 8;
        float4 v0 = *(const float4*)p;
        float4 v1 = *(const float4*)(p + 4);
        uint4 u;
        u.x = pack_bf16_trunc(v0.x, v0.y);
        u.y = pack_bf16_trunc(v0.z, v0.w);
        u.z = pack_bf16_trunc(v1.x, v1.y);
        u.w = pack_bf16_trunc(v1.z, v1.w);
        *(uint4*)&As[(m * 64 + (c2 ^ m)) * 8] = u;
    }
    __syncthreads();               // the ONLY barrier before the epilogue

    // ---- barrier-free main loop
    const unsigned short* Bw = Btf + (size_t)(w * 8) * 16 * 64 * 8;  // frag_n base
    f32x4 acc[4][8] = {};
    s16x8 bfr[2][8];
    #pragma unroll
    for (int j = 0; j < 8; ++j)
        bfr[0][j] = *(const s16x8*)(Bw + ((size_t)(j * 16 + 0) * 64 + lane) * 8);

    #pragma unroll
    for (int kk = 0; kk < 16; ++kk) {
        int cur = kk & 1;
        if (kk < 15) {
            #pragma unroll
            for (int j = 0; j < 8; ++j)
                bfr[cur ^ 1][j] =
                    *(const s16x8*)(Bw + ((size_t)(j * 16 + kk + 1) * 64 + lane) * 8);
        }
        s16x8 af[4];
        #pragma unroll
        for (int i = 0; i < 4; ++i) {
            int m = i * 16 + lcol;
            af[i] = *(const s16x8*)&As[(m * 64 + ((kk * 4 + q) ^ m)) * 8];
        }
        #pragma unroll
        for (int i = 0; i < 4; ++i)
            #pragma unroll
            for (int j = 0; j < 8; ++j)
                acc[i][j] = __builtin_amdgcn_mfma_f32_16x16x32_bf16(
                    af[i], bfr[cur][j], acc[i][j], 0, 0, 0);
    }

    // ---- epilogue: cij[row] = sum over 512 cols of tanh(acc+cvec)*V.
    // C/D layout: col = lane&15, row = (lane>>4)*4 + reg.
    __syncthreads();               // done with As; reuse as reduction buffer
    float* red = (float*)As;       // 4 waves x 64 rows
    int b = m0 >> 12;
    float cvv[8], Vv[8];
    #pragma unroll
    for (int j = 0; j < 8; ++j) {
        int h = wn + j * 16 + lcol;
        cvv[j] = cvec[b * HH + h];
        Vv[j] = V[h];
    }
    #pragma unroll
    for (int i = 0; i < 4; ++i) {
        #pragma unroll
        for (int r = 0; r < 4; ++r) {
            float s = 0.0f;
            #pragma unroll
            for (int j = 0; j < 8; ++j)
                s = fmaf(tanh_fast(acc[i][j][r] + cvv[j]), Vv[j], s);
            s += __shfl_xor(s, 1);
            s += __shfl_xor(s, 2);
            s += __shfl_xor(s, 4);
            s += __shfl_xor(s, 8);
            if (lcol == 0)
                red[w * 64 + i * 16 + q * 4 + r] = s;
        }
    }
    __syncthreads();
    if (tid < 64)
        cij[m0 + tid] = red[tid] + red[64 + tid] + red[128 + tid] + red[192 + tid];
}

// ---------------------------------------------------------------------------
// softmax over T per batch.
__global__ void k_softmax(const float* __restrict__ cij, float* __restrict__ alphas) {
    int b = blockIdx.x, tid = threadIdx.x;
    const float* row = cij + (size_t)b * TT;
    __shared__ float red[4];
    float m = -1e30f;
    for (int t = tid; t < TT; t += 256) m = fmaxf(m, row[t]);
    #pragma unroll
    for (int o = 1; o < 64; o <<= 1) m = fmaxf(m, __shfl_xor(m, o));
    if ((tid & 63) == 0) red[tid >> 6] = m;
    __syncthreads();
    m = fmaxf(fmaxf(red[0], red[1]), fmaxf(red[2], red[3]));
    __syncthreads();
    float sum = 0.0f;
    for (int t = tid; t < TT; t += 256) sum += __expf(row[t] - m);
    #pragma unroll
    for (int o = 1; o < 64; o <<= 1) sum += __shfl_xor(sum, o);
    if ((tid & 63) == 0) red[tid >> 6] = sum;
    __syncthreads();
    float inv = 1.0f / (red[0] + red[1] + red[2] + red[3]);
    for (int t = tid; t < TT; t += 256)
        alphas[(size_t)b * TT + t] = __expf(row[t] - m) * inv;
}

// partial weighted sums, no atomics; 4 independent load streams.
// block = (b, 64-t chunk) -> pw[b][chunk][0:512]. 2048 blocks, 268MB stream.
__global__ void k_wsum(const float* __restrict__ e, const float* __restrict__ alphas,
                       float* __restrict__ pw) {
    int b = blockIdx.x >> 6;
    int chunk = blockIdx.x & 63;
    int tid = threadIdx.x;
    int half = tid >> 7, f4 = tid & 127;
    const float* base = e + (size_t)b * TT * DD + (size_t)chunk * 64 * DD + f4 * 4;
    const float* al = alphas + (size_t)b * TT + chunk * 64;
    f32x4 a0 = {0,0,0,0}, a1 = {0,0,0,0}, a2 = {0,0,0,0}, a3 = {0,0,0,0};
    for (int it = 0; it < 8; ++it) {
        int t = it * 8 + half;
        float w0 = al[t], w1 = al[t + 2], w2 = al[t + 4], w3 = al[t + 6];
        a0 += w0 * *(const f32x4*)(base + (size_t)t * DD);
        a1 += w1 * *(const f32x4*)(base + (size_t)(t + 2) * DD);
        a2 += w2 * *(const f32x4*)(base + (size_t)(t + 4) * DD);
        a3 += w3 * *(const f32x4*)(base + (size_t)(t + 6) * DD);
    }
    a0 += a1; a2 += a3; a0 += a2;
    __shared__ f32x4 red[128];
    if (half == 1) red[f4] = a0;
    __syncthreads();
    if (half == 0) {
        a0 += red[f4];
        *(f32x4*)&pw[((size_t)(b * 64 + chunk)) * DD + f4 * 4] = a0;
    }
}

// out[b,d] = sum_chunk pw[b][chunk][d]. 4MB read.
__global__ void k_wred(const float* __restrict__ pw, float* __restrict__ out) {
    int b = blockIdx.x, tid = threadIdx.x;
    float2 acc = {0.0f, 0.0f};
    const float* base = pw + (size_t)b * 64 * DD;
    #pragma unroll 4
    for (int c = 0; c < 64; ++c) {
        float2 v = *(const float2*)(base + (size_t)c * DD + tid * 2);
        acc.x += v.x;
        acc.y += v.y;
    }
    *(float2*)&out[b * DD + tid * 2] = acc;
}

// ---------------------------------------------------------------------------
extern "C" void kernel_launch(void* const* d_in, const int* in_sizes, int n_in,
                              void* d_out, int out_size, void* d_ws, size_t ws_size,
                              hipStream_t stream) {
    const float* hs   = (const float*)d_in[0];   // [32,512]
    const float* e    = (const float*)d_in[1];   // [32,4096,512]
    const float* W    = (const float*)d_in[2];   // [512,512]
    const float* U    = (const float*)d_in[3];   // [512,512]
    const float* V    = (const float*)d_in[4];   // [512]
    const float* bias = (const float*)d_in[5];   // [512]
    const float* Wa   = (const float*)d_in[6];   // [512,512]
    const float* ba   = (const float*)d_in[7];   // [512]

    float* out    = (float*)d_out;               // [32,512] then alphas [32,4096]
    float* alphas = out + BB * DD;

    float*          cij  = (float*)d_ws;                              // 512 KB
    float*          cvec = (float*)((char*)d_ws + 524288);            // 64 KB
    unsigned short* Btf  = (unsigned short*)((char*)d_ws + 589824);   // 512 KB bf16
    float*          pw   = (float*)((char*)d_ws + 1179648);           // 4 MB

    // no memsets: every workspace word consumed is written first
    // (cvec/Btf by k_prep, cij stored by k_gemm_tanh, pw by k_wsum).

    k_prep<<<96, 256, 0, stream>>>(hs, W, bias, Wa, ba, U, cvec, Btf);
    k_gemm_tanh<<<2048, 256, 0, stream>>>(e, Btf, cvec, V, cij);
    k_softmax<<<BB, 256, 0, stream>>>(cij, alphas);
    k_wsum<<<BB * 64, 256, 0, stream>>>(e, alphas, pw);
    k_wred<<<BB, 256, 0, stream>>>(pw, out);
}